// Round 4
// baseline (91.890 us; speedup 1.0000x reference)
//
#include <hip/hip_runtime.h>
#include <hip/hip_bf16.h>

#define MD 128   // D
#define KC 8     // K capsules
#define KD 16    // DD
#define MN 16    // M neighbors
#define QS 20    // LDS row stride (floats): 16B-aligned, bank-spread

typedef short          s16x2 __attribute__((ext_vector_type(2)));
typedef unsigned short u16x2 __attribute__((ext_vector_type(2)));

static __device__ __forceinline__ float lo_bf(unsigned int w){ union{unsigned int i;float f;}c; c.i=w<<16;        return c.f; }
static __device__ __forceinline__ float hi_bf(unsigned int w){ union{unsigned int i;float f;}c; c.i=w&0xffff0000u; return c.f; }
static __device__ __forceinline__ float bf2f1(unsigned short u){ union{unsigned int i;float f;}c; c.i=((unsigned int)u)<<16; return c.f; }

static __device__ __forceinline__ float fast_rsq(float x){ return __builtin_amdgcn_rsqf(x); }
static __device__ __forceinline__ float fast_rcp(float x){ return __builtin_amdgcn_rcpf(x); }

// ---- packed bf16 sort keys: monotone bijection bf16 -> u16 ----
// neg: key = ~u ; pos: key = u | 0x8000   (order-preserving, exact)
static __device__ __forceinline__ unsigned bfkey(unsigned u) {
    s16x2 s = __builtin_bit_cast(s16x2, u) >> 15;            // v_pk_ashrrev_i16
    return u ^ (__builtin_bit_cast(unsigned, s) | 0x80008000u);
}
static __device__ __forceinline__ unsigned bfunkey(unsigned y) {
    s16x2 s = __builtin_bit_cast(s16x2, ~y) >> 15;
    return y ^ (__builtin_bit_cast(unsigned, s) | 0x80008000u);
}
static __device__ __forceinline__ unsigned pminu(unsigned a, unsigned b) {
    return __builtin_bit_cast(unsigned, __builtin_elementwise_min(
        __builtin_bit_cast(u16x2, a), __builtin_bit_cast(u16x2, b)));
}
static __device__ __forceinline__ unsigned pmaxu(unsigned a, unsigned b) {
    return __builtin_bit_cast(unsigned, __builtin_elementwise_max(
        __builtin_bit_cast(u16x2, a), __builtin_bit_cast(u16x2, b)));
}
static __device__ __forceinline__ void pcas(unsigned& x, unsigned& y) {
    unsigned lo = pminu(x, y), hi = pmaxu(x, y); x = lo; y = hi;
}
// Batcher odd-even mergesort, 8 elems, 19 CAS — two columns per op (packed)
static __device__ __forceinline__ void psort8(unsigned a[8]) {
    pcas(a[0],a[1]); pcas(a[2],a[3]); pcas(a[4],a[5]); pcas(a[6],a[7]);
    pcas(a[0],a[2]); pcas(a[1],a[3]); pcas(a[4],a[6]); pcas(a[5],a[7]);
    pcas(a[1],a[2]); pcas(a[5],a[6]);
    pcas(a[0],a[4]); pcas(a[2],a[6]); pcas(a[2],a[4]);
    pcas(a[1],a[5]); pcas(a[3],a[7]); pcas(a[3],a[5]);
    pcas(a[1],a[2]); pcas(a[3],a[4]); pcas(a[5],a[6]);
}
// b7/b8 (8th/9th smallest of 16) per packed column, returned un-keyed (bf16 bits)
static __device__ __forceinline__ void pmed16(unsigned a[16], unsigned& w7, unsigned& w8) {
    psort8(a); psort8(a + 8);
    const unsigned* u = a; const unsigned* v = a + 8;
    unsigned t7 =             pminu(u[7], v[0]);
    t7 = pmaxu(t7, pminu(u[6], v[1]));
    t7 = pmaxu(t7, pminu(u[5], v[2]));
    t7 = pmaxu(t7, pminu(u[4], v[3]));
    t7 = pmaxu(t7, pminu(u[3], v[4]));
    t7 = pmaxu(t7, pminu(u[2], v[5]));
    t7 = pmaxu(t7, pminu(u[1], v[6]));
    t7 = pmaxu(t7, pminu(u[0], v[7]));
    unsigned t8 = pmaxu(u[0], v[0]);
    t8 = pmaxu(t8, pminu(u[7], v[1]));
    t8 = pmaxu(t8, pminu(u[6], v[2]));
    t8 = pmaxu(t8, pminu(u[5], v[3]));
    t8 = pmaxu(t8, pminu(u[4], v[4]));
    t8 = pmaxu(t8, pminu(u[3], v[5]));
    t8 = pmaxu(t8, pminu(u[2], v[6]));
    t8 = pmaxu(t8, pminu(u[1], v[7]));
    w7 = bfunkey(t7); w8 = bfunkey(t8);
}

// ---- scalar f32 median (fallback path for f32 dtype) ----
static __device__ __forceinline__ void cas(float& x, float& y) {
    float lo = fminf(x, y), hi = fmaxf(x, y); x = lo; y = hi;
}
static __device__ __forceinline__ void sort8f(float a[8]) {
    cas(a[0],a[1]); cas(a[2],a[3]); cas(a[4],a[5]); cas(a[6],a[7]);
    cas(a[0],a[2]); cas(a[1],a[3]); cas(a[4],a[6]); cas(a[5],a[7]);
    cas(a[1],a[2]); cas(a[5],a[6]);
    cas(a[0],a[4]); cas(a[2],a[6]); cas(a[2],a[4]);
    cas(a[1],a[5]); cas(a[3],a[7]); cas(a[3],a[5]);
    cas(a[1],a[2]); cas(a[3],a[4]); cas(a[5],a[6]);
}
static __device__ __forceinline__ float med17f(float a[16], float self) {
    sort8f(a); sort8f(a + 8);
    const float* u = a; const float* v = a + 8;
    float t7 =            fminf(u[7], v[0]);
    t7 = fmaxf(t7, fminf(u[6], v[1])); t7 = fmaxf(t7, fminf(u[5], v[2]));
    t7 = fmaxf(t7, fminf(u[4], v[3])); t7 = fmaxf(t7, fminf(u[3], v[4]));
    t7 = fmaxf(t7, fminf(u[2], v[5])); t7 = fmaxf(t7, fminf(u[1], v[6]));
    t7 = fmaxf(t7, fminf(u[0], v[7]));
    float t8 = fmaxf(u[0], v[0]);
    t8 = fmaxf(t8, fminf(u[7], v[1])); t8 = fmaxf(t8, fminf(u[6], v[2]));
    t8 = fmaxf(t8, fminf(u[5], v[3])); t8 = fmaxf(t8, fminf(u[4], v[4]));
    t8 = fmaxf(t8, fminf(u[3], v[5])); t8 = fmaxf(t8, fminf(u[2], v[6]));
    t8 = fmaxf(t8, fminf(u[1], v[7]));
    return __builtin_amdgcn_fmed3f(self, t7, t8);
}

// full-rate VALU lane exchange via DPP
template<int CTRL>
static __device__ __forceinline__ float dpp_mov(float v) {
    return __int_as_float(__builtin_amdgcn_update_dpp(
        0, __float_as_int(v), CTRL, 0xF, 0xF, false));
}
static __device__ __forceinline__ float rsum_quad(float v) {
    v += dpp_mov<0xB1>(v);   // quad_perm xor1
    v += dpp_mov<0x4E>(v);   // quad_perm xor2
    return v;
}
static __device__ __forceinline__ float rsum_caps(float v) {
    v += __shfl_xor(v, 4);
    v += dpp_mov<0x128>(v);  // row_ror:8 == xor8
    v += __shfl_xor(v, 16);
    return v;
}
static __device__ __forceinline__ float rmax_caps(float v) {
    v = fmaxf(v, __shfl_xor(v, 4));
    v = fmaxf(v, dpp_mov<0x128>(v));
    v = fmaxf(v, __shfl_xor(v, 16));
    return v;
}

// flag[0] = 1 if h is bf16, 0 if f32
__global__ void detect_dtype(const unsigned short* __restrict__ h, int* __restrict__ flag) {
    int l = threadIdx.x;
    float m = 0.f;
    for (int i = l; i < 1024; i += 64) {
        float v = bf2f1(h[i]);
        v = (v != v) ? 1e30f : fabsf(v);
        m = fmaxf(m, v);
    }
    #pragma unroll
    for (int off = 1; off < 64; off <<= 1) m = fmaxf(m, __shfl_xor(m, off));
    if (l == 0) flag[0] = (m < 1000.0f) ? 1 : 0;
}

template<bool BF>
__global__ __launch_bounds__(256)
void attn_fwd(const void* __restrict__ hraw,
              const int* __restrict__ nbr,
              const void* __restrict__ qry,
              const void* __restrict__ keyw,
              const int* __restrict__ iterat_p,
              const int* __restrict__ flag_p,
              void* __restrict__ out,
              int n_nodes)
{
    if (flag_p[0] != (BF ? 1 : 0)) return;  // uniform exit; kernel has no barriers

    const int tid  = threadIdx.x;
    const int wid  = tid >> 6;
    const int l    = tid & 63;
    const int sub  = l & 31;
    const int half = (l >> 5) & 1;
    const int k    = sub >> 2;
    const int q4   = sub & 3;

    // per-wave private Q / K^T copies -> NO __syncthreads (no vmcnt(0) drain)
    __shared__ float q_s [4][16 * QS];
    __shared__ float kt_s[4][16 * QS];
    float* qs  = q_s [wid];
    float* kts = kt_s[wid];

    const int iterat = iterat_p[0];

    for (int base = blockIdx.x * 8; base < n_nodes; base += gridDim.x * 8) {
        int n = base + wid * 2 + half;
        if (n >= n_nodes) n = n_nodes - 1;   // duplicate work, identical writes

        // ---- issue loads in priority order (compiler emits counted vmcnt) ----
        int nnb = base + wid * 2 + ((l >> 4) & 1);
        if (nnb >= n_nodes) nnb = n_nodes - 1;
        const int nbv = nbr[nnb * MN + (l & 15)];          // 1: neighbor indices

        uint2  hp_b; float4 hp_f;                          // 2: self row
        if (BF) hp_b = ((const uint2*)hraw)[(size_t)n * (MD / 8) * 2 + sub];
        else    hp_f = ((const float4*)hraw)[(size_t)n * (MD / 4) + sub];

        uint2  qw_b, kw_b; float4 qw_f, kw_f;              // 3: Q, K (elems 4l..4l+3)
        if (BF) { qw_b = ((const uint2 *)qry)[l]; kw_b = ((const uint2 *)keyw)[l]; }
        else    { qw_f = ((const float4*)qry)[l]; kw_f = ((const float4*)keyw)[l]; }

        uint2  rb[16]; float4 rf[16];                      // 4: the 16-row gather
        #pragma unroll
        for (int m = 0; m < MN; ++m) {
            int ia  = __builtin_amdgcn_readlane(nbv, m);
            int ib  = __builtin_amdgcn_readlane(nbv, m + 16);
            int idx = half ? ib : ia;
            if (BF) rb[m] = *(const uint2*) ((const char*)hraw + (((unsigned)idx << 8) + (unsigned)sub * 8u));
            else    rf[m] = *(const float4*)((const char*)hraw + (((unsigned)idx << 9) + (unsigned)sub * 16u));
        }

        // ---- stage Q row-major + K^T into this wave's LDS copy ----
        {
            int e = l >> 2, f0 = (l & 3) * 4;
            float4 qv, kv;
            if (BF) {
                qv.x = lo_bf(qw_b.x); qv.y = hi_bf(qw_b.x); qv.z = lo_bf(qw_b.y); qv.w = hi_bf(qw_b.y);
                kv.x = lo_bf(kw_b.x); kv.y = hi_bf(kw_b.x); kv.z = lo_bf(kw_b.y); kv.w = hi_bf(kw_b.y);
            } else { qv = qw_f; kv = kw_f; }
            *(float4*)&qs[e * QS + f0] = qv;
            kts[(f0 + 0) * QS + e] = kv.x;
            kts[(f0 + 1) * QS + e] = kv.y;
            kts[(f0 + 2) * QS + e] = kv.z;
            kts[(f0 + 3) * QS + e] = kv.w;
        }

        // ---- self row normalize (4 dims/lane) ----
        float hp[4];
        if (BF) { hp[0]=lo_bf(hp_b.x); hp[1]=hi_bf(hp_b.x); hp[2]=lo_bf(hp_b.y); hp[3]=hi_bf(hp_b.y); }
        else    { hp[0]=hp_f.x; hp[1]=hp_f.y; hp[2]=hp_f.z; hp[3]=hp_f.w; }
        float ss = 0;
        #pragma unroll
        for (int i = 0; i < 4; ++i) ss = fmaf(hp[i], hp[i], ss);
        ss = rsum_quad(ss);
        float inv = fast_rsq(fmaxf(ss, 1e-24f));
        float hc[4];
        #pragma unroll
        for (int i = 0; i < 4; ++i) hc[i] = hp[i] * inv;

        // ---- kk = hc @ K ; w = Q @ kk  (quad DPP broadcasts + LDS rows) ----
        float hcA[4][4];
        #pragma unroll
        for (int j = 0; j < 4; ++j) {
            hcA[0][j] = dpp_mov<0x00>(hc[j]); hcA[1][j] = dpp_mov<0x55>(hc[j]);
            hcA[2][j] = dpp_mov<0xAA>(hc[j]); hcA[3][j] = dpp_mov<0xFF>(hc[j]);
        }
        float kk[4];
        #pragma unroll
        for (int i = 0; i < 4; ++i) {
            const float* row = &kts[(q4 * 4 + i) * QS];
            float acc = 0;
            #pragma unroll
            for (int r = 0; r < 4; ++r) {
                float4 kr = *(const float4*)(row + r * 4);
                acc = fmaf(hcA[r][0], kr.x, acc); acc = fmaf(hcA[r][1], kr.y, acc);
                acc = fmaf(hcA[r][2], kr.z, acc); acc = fmaf(hcA[r][3], kr.w, acc);
            }
            kk[i] = acc;
        }
        float kkA[4][4];
        #pragma unroll
        for (int j = 0; j < 4; ++j) {
            kkA[0][j] = dpp_mov<0x00>(kk[j]); kkA[1][j] = dpp_mov<0x55>(kk[j]);
            kkA[2][j] = dpp_mov<0xAA>(kk[j]); kkA[3][j] = dpp_mov<0xFF>(kk[j]);
        }
        float w[4];
        #pragma unroll
        for (int i = 0; i < 4; ++i) {
            const float* row = &qs[(q4 * 4 + i) * QS];
            float acc = 0;
            #pragma unroll
            for (int r = 0; r < 4; ++r) {
                float4 qr = *(const float4*)(row + r * 4);
                acc = fmaf(kkA[r][0], qr.x, acc); acc = fmaf(kkA[r][1], qr.y, acc);
                acc = fmaf(kkA[r][2], qr.z, acc); acc = fmaf(kkA[r][3], qr.w, acc);
            }
            w[i] = acc;
        }

        // ---- att = softmax_k(hc . w)   (hc.w == q.kk) ----
        float lg = 0;
        #pragma unroll
        for (int i = 0; i < 4; ++i) lg = fmaf(hc[i], w[i], lg);
        float logit = rsum_quad(lg);
        float mx  = rmax_caps(logit);
        float ex  = __expf(logit - mx);
        float att = ex * fast_rcp(rsum_caps(ex));

        // ---- column sums (sn, s2) over the 16 gathered rows ----
        float sn[4] = {0,0,0,0}, s2[4] = {0,0,0,0};
        #pragma unroll
        for (int m = 0; m < 16; ++m) {
            float x0, x1, x2, x3;
            if (BF) { x0=lo_bf(rb[m].x); x1=hi_bf(rb[m].x); x2=lo_bf(rb[m].y); x3=hi_bf(rb[m].y); }
            else    { x0=rf[m].x; x1=rf[m].y; x2=rf[m].z; x3=rf[m].w; }
            sn[0]+=x0; sn[1]+=x1; sn[2]+=x2; sn[3]+=x3;
            s2[0]=fmaf(x0,x0,s2[0]); s2[1]=fmaf(x1,x1,s2[1]);
            s2[2]=fmaf(x2,x2,s2[2]); s2[3]=fmaf(x3,x3,s2[3]);
        }

        // ---- medians: packed-u16 (bf16 exact) or scalar f32 ----
        float mid[4];
        if (BF) {
            unsigned ka[16];
            #pragma unroll
            for (int m = 0; m < 16; ++m) ka[m] = bfkey(rb[m].x);
            unsigned w7, w8; pmed16(ka, w7, w8);
            mid[0] = __builtin_amdgcn_fmed3f(hc[0], lo_bf(w7), lo_bf(w8));
            mid[1] = __builtin_amdgcn_fmed3f(hc[1], hi_bf(w7), hi_bf(w8));
            unsigned kb[16];
            #pragma unroll
            for (int m = 0; m < 16; ++m) kb[m] = bfkey(rb[m].y);
            pmed16(kb, w7, w8);
            mid[2] = __builtin_amdgcn_fmed3f(hc[2], lo_bf(w7), lo_bf(w8));
            mid[3] = __builtin_amdgcn_fmed3f(hc[3], hi_bf(w7), hi_bf(w8));
        } else {
            #pragma unroll
            for (int c = 0; c < 4; ++c) {
                float a[16];
                #pragma unroll
                for (int m = 0; m < 16; ++m)
                    a[m] = (c==0) ? rf[m].x : (c==1) ? rf[m].y : (c==2) ? rf[m].z : rf[m].w;
                mid[c] = med17f(a, hc[c]);
            }
        }
        #pragma unroll
        for (int c = 0; c < 4; ++c) {
            float t2 = fmaf(hc[c], hc[c], s2[c]);
            mid[c] *= fast_rsq(fmaxf(t2, 1e-24f));
        }

        // diag[k] = (sum_m nb[m,k]) . w[k]
        float dgl = 0;
        #pragma unroll
        for (int i = 0; i < 4; ++i) dgl = fmaf(sn[i], w[i], dgl);
        float dg = rsum_quad(dgl);

        // cov_d = sum_k diag[k]*(hc-mid)^2  (row-independent)
        float cv[4];
        #pragma unroll
        for (int i = 0; i < 4; ++i) {
            float t = hc[i] - mid[i];
            cv[i] = rsum_caps(dg * t * t);
        }

        // dets/left, exact NaN semantics of the reference
        float lsl = 0;
        #pragma unroll
        for (int i = 0; i < 4; ++i) {
            float lr = __logf(cv[i]);
            lr = (lr != lr) ? 1e-6f : lr;
            lsl += __logf(lr);
        }
        float ls   = rsum_quad(lsl);
        float dets = __expf(ls);
        const float coef = 5.822108e-7f;  // 1/sqrt((2*pi)^16 / 2)
        float left = coef * fast_rsq(dets + 1e-6f);

        // ---- iterative routing ----
        float ah[4], ix[4];
        #pragma unroll
        for (int i = 0; i < 4; ++i) ah[i] = att * hc[i];
        #pragma unroll
        for (int i = 0; i < 4; ++i) ix[i] = rsum_caps(ah[i]);

        for (int it = 0; it < iterat; ++it) {
            float rsl = 0;
            #pragma unroll
            for (int i = 0; i < 4; ++i) {
                float df = ix[i] - hc[i];
                rsl = fmaf(cv[i] * df, df, rsl);
            }
            float rs   = rsum_quad(rsl);
            float prob = left * __expf(-0.5f * rs);
            float p2   = rsum_caps(prob * prob);
            float pn   = prob * fast_rsq(fmaxf(p2, 1e-24f));
            pn = (pn != pn) ? 1e-6f : pn;
            float den = rsum_caps(att * pn);
            float num[4];
            #pragma unroll
            for (int i = 0; i < 4; ++i) num[i] = rsum_caps(pn * ah[i]);
            float rr = fast_rcp(den + 1e-9f);
            #pragma unroll
            for (int i = 0; i < 4; ++i) ix[i] = num[i] * rr;
        }

        // ---- x = normalize(ix); write outputs ----
        float xs = 0;
        #pragma unroll
        for (int i = 0; i < 4; ++i) xs = fmaf(ix[i], ix[i], xs);
        xs = rsum_quad(xs);
        float xinv = fast_rsq(fmaxf(xs, 1e-24f));

        if (BF) {
            if (sub < 4) {
                __hip_bfloat16 b0 = __float2bfloat16(ix[0] * xinv);
                __hip_bfloat16 b1 = __float2bfloat16(ix[1] * xinv);
                __hip_bfloat16 b2 = __float2bfloat16(ix[2] * xinv);
                __hip_bfloat16 b3 = __float2bfloat16(ix[3] * xinv);
                uint2 o;
                o.x = (unsigned)(*(unsigned short*)&b0) | ((unsigned)(*(unsigned short*)&b1) << 16);
                o.y = (unsigned)(*(unsigned short*)&b2) | ((unsigned)(*(unsigned short*)&b3) << 16);
                *(uint2*)((char*)out + (size_t)n * 32 + q4 * 8) = o;
            }
            if (q4 == 0) {
                __hip_bfloat16 ba = __float2bfloat16(att);
                ((unsigned short*)out)[(size_t)n_nodes * KD + (size_t)n * KC + k] =
                    *(unsigned short*)&ba;
            }
        } else {
            if (sub < 4) {
                float4 o;
                o.x = ix[0] * xinv; o.y = ix[1] * xinv; o.z = ix[2] * xinv; o.w = ix[3] * xinv;
                *(float4*)((float*)out + (size_t)n * KD + q4 * 4) = o;
            }
            if (q4 == 0) ((float*)out)[(size_t)n_nodes * KD + (size_t)n * KC + k] = att;
        }
    }
}

extern "C" void kernel_launch(void* const* d_in, const int* in_sizes, int n_in,
                              void* d_out, int out_size, void* d_ws, size_t ws_size,
                              hipStream_t stream) {
    const void* h    = d_in[0];
    const int*  nbr  = (const int*)d_in[1];
    const void* qry  = d_in[2];
    const void* keyw = (const void*)d_in[3];
    const int*  iterat_p = (const int*)d_in[4];

    int n_nodes = in_sizes[0] / MD;
    int* flag = (int*)d_ws;

    detect_dtype<<<1, 64, 0, stream>>>((const unsigned short*)h, flag);

    int full = (n_nodes + 7) / 8;               // 8 nodes/block
    int small = full < 1024 ? full : 1024;      // dead-dtype path: cheap exit, grid-strided if live
    attn_fwd<true ><<<full,  256, 0, stream>>>(h, nbr, qry, keyw, iterat_p, flag, d_out, n_nodes);
    attn_fwd<false><<<small, 256, 0, stream>>>(h, nbr, qry, keyw, iterat_p, flag, d_out, n_nodes);
}